// Round 8
// baseline (637.745 us; speedup 1.0000x reference)
//
#include <hip/hip_runtime.h>
#include <math.h>

#define NPTS 4096

typedef __attribute__((ext_vector_type(8))) short bf16x8;
typedef __attribute__((ext_vector_type(16))) float f32x16;

// liveness pin: forbid rematerialization / load sinking (round-5 lesson)
#define KEEP(x) asm volatile("" : "+v"(x))

__device__ __forceinline__ f32x16 zero16() {
  f32x16 z;
#pragma unroll
  for (int i = 0; i < 16; ++i) z[i] = 0.f;
  return z;
}

// branchless sorted-descending top-7 insert (round-8: wave take-prob ~1 makes
// the branchy version pay its body every site + exec-mask overhead; this is
// 7 cmp + 26 cndmask, fully static indexing per rule #20)
__device__ __forceinline__ void ins7(float v, int i, float* s, int* j) {
  bool c[7];
#pragma unroll
  for (int t = 0; t < 7; ++t) c[t] = v > s[t];
#pragma unroll
  for (int t = 6; t >= 1; --t) {   // t reads s[t-1] before iteration t-1 writes it
    s[t] = c[t] ? (c[t - 1] ? s[t - 1] : v) : s[t];
    j[t] = c[t] ? (c[t - 1] ? j[t - 1] : i) : j[t];
  }
  s[0] = c[0] ? v : s[0];
  j[0] = c[0] ? i : j[0];
}

// classic insert (used only in the once-per-block final merge)
__device__ __forceinline__ void top7_insert(float v, int i, float* v7, int* i7,
                                            float& vmin, int& pmin) {
  if (v > vmin) {
#pragma unroll
    for (int t = 0; t < 7; ++t)
      if (t == pmin) { v7[t] = v; i7[t] = i; }
    vmin = v7[0]; pmin = 0;
#pragma unroll
    for (int t = 1; t < 7; ++t)
      if (v7[t] < vmin) { vmin = v7[t]; pmin = t; }
  }
}

__device__ __forceinline__ unsigned bf16pack(float a, float b) {
  unsigned ua = __float_as_uint(a); ua = (ua + 0x7FFFu + ((ua >> 16) & 1u)) >> 16;
  unsigned ub = __float_as_uint(b); ub = (ub + 0x7FFFu + ((ub >> 16) & 1u)) >> 16;
  return ua | (ub << 16);
}

// ---------------------------------------------------------------------------
// K1: normalize + cast + write FRAGMENT-MAJOR layout.
// Fsw[b][mt][kc(24)][lane(64)][8elem]; Csw[b][mt][kc(6)][lane(64)][8elem]
// ---------------------------------------------------------------------------
__global__ __launch_bounds__(64) void norm_cast(const float* __restrict__ codes,
                                                const float* __restrict__ feats,
                                                unsigned short* __restrict__ Fsw,
                                                unsigned short* __restrict__ Csw,
                                                float* __restrict__ invc) {
  const int row = blockIdx.x;            // 0 .. 8191
  const int lane = threadIdx.x;
  const int b = row >> 12, mt = (row >> 5) & 127, rl = row & 31;

  const float* f = feats + (size_t)row * 384;
  float v[8];
  float ss = 0.f;
  if (lane < 48) {
    float4 p0 = *(const float4*)(f + lane * 8);
    float4 p1 = *(const float4*)(f + lane * 8 + 4);
    v[0] = p0.x; v[1] = p0.y; v[2] = p0.z; v[3] = p0.w;
    v[4] = p1.x; v[5] = p1.y; v[6] = p1.z; v[7] = p1.w;
#pragma unroll
    for (int e = 0; e < 8; ++e) ss = fmaf(v[e], v[e], ss);
  }
#pragma unroll
  for (int m = 1; m <= 32; m <<= 1) ss += __shfl_xor(ss, m, 64);
  const float inv = rsqrtf(ss + 1e-8f);
  if (lane < 48) {
    uint4 o;
    o.x = bf16pack(v[0] * inv, v[1] * inv);
    o.y = bf16pack(v[2] * inv, v[3] * inv);
    o.z = bf16pack(v[4] * inv, v[5] * inv);
    o.w = bf16pack(v[6] * inv, v[7] * inv);
    const int kc = lane >> 1, hs = lane & 1;
    *(uint4*)(Fsw + (((size_t)(b * 128 + mt) * 24 + kc) << 9) + (hs * 32 + rl) * 8) = o;
  }

  const float* c = codes + (size_t)row * 90;
  float cv[8];
#pragma unroll
  for (int e = 0; e < 8; ++e) cv[e] = 0.f;
  if (lane < 11) {
    float4 p0 = *(const float4*)(c + lane * 8);
    float4 p1 = *(const float4*)(c + lane * 8 + 4);
    cv[0] = p0.x; cv[1] = p0.y; cv[2] = p0.z; cv[3] = p0.w;
    cv[4] = p1.x; cv[5] = p1.y; cv[6] = p1.z; cv[7] = p1.w;
  } else if (lane == 11) {
    cv[0] = c[88]; cv[1] = c[89];
  }
  float cs = 0.f;
#pragma unroll
  for (int e = 0; e < 8; ++e) cs = fmaf(cv[e], cv[e], cs);
#pragma unroll
  for (int m = 1; m <= 32; m <<= 1) cs += __shfl_xor(cs, m, 64);
  const float cinv = rsqrtf(cs + 1e-8f);
  if (lane < 12) {
    uint4 o;
    o.x = bf16pack(cv[0] * cinv, cv[1] * cinv);
    o.y = bf16pack(cv[2] * cinv, cv[3] * cinv);
    o.z = bf16pack(cv[4] * cinv, cv[5] * cinv);
    o.w = bf16pack(cv[6] * cinv, cv[7] * cinv);
    const int kc = lane >> 1, hs = lane & 1;
    *(uint4*)(Csw + (((size_t)(b * 128 + mt) * 6 + kc) << 9) + (hs * 32 + rl) * 8) = o;
  }
  if (lane == 0) invc[row] = cinv;
}

// ---------------------------------------------------------------------------
// K2: feature similarities via 32x32x16 bf16 MFMA (swapped: D[m][q]) + top-7.
// 1024 thr / 16 waves (4 waves/SIMD); wave w sweeps m-tiles [w*8, w*8+8).
// XCD-batch mapping: XCDs 0-3 -> batch 0, 4-7 -> batch 1 (3 MB panel per L2).
// ---------------------------------------------------------------------------
__global__ __launch_bounds__(1024, 1) void knn_mfma(const unsigned short* __restrict__ Fsw,
                                                    int* __restrict__ knn_out) {
  __shared__ float cval[16][32][7];
  __shared__ int   cidx[16][32][7];
  const int g = blockIdx.x;              // 0..255
  const int xcd = g & 7;
  const int b = xcd >> 2;
  const int qt = ((g >> 3) << 2) | (xcd & 3);   // 0..127
  const int q0 = qt * 32;
  const int tid = threadIdx.x;
  const int w = tid >> 6;                // 0..15
  const int lane = tid & 63;
  const int lo = lane & 31, hi4 = (lane >> 5) * 4;
  const unsigned short* Fb = Fsw + (size_t)b * 128 * 24 * 512;

  bf16x8 bfr[24];
  {
    const unsigned short* qb = Fb + ((size_t)qt * 24) * 512 + lane * 8;
#pragma unroll
    for (int t = 0; t < 24; ++t) bfr[t] = *(const bf16x8*)(qb + t * 512);
#pragma unroll
    for (int t = 0; t < 24; ++t) KEEP(bfr[t]);
  }
  float s7[7]; int j7[7];
#pragma unroll
  for (int t = 0; t < 7; ++t) { s7[t] = -1e30f; j7[t] = 0; }

  // wave w sweeps m-tiles [w*8, w*8+8)
  const unsigned short* ab = Fb + ((size_t)(w * 8) * 24) * 512 + lane * 8;

  bf16x8 a0[12], a1[12];
#pragma unroll
  for (int t = 0; t < 12; ++t) a0[t] = *(const bf16x8*)(ab + t * 512);
#pragma unroll
  for (int t = 0; t < 12; ++t) KEEP(a0[t]);

  for (int mt = 0; mt < 8; ++mt) {
    const unsigned short* art = ab + (size_t)mt * 24 * 512;
    // prefetch second K-half of this tile
#pragma unroll
    for (int t = 0; t < 12; ++t) a1[t] = *(const bf16x8*)(art + (12 + t) * 512);
#pragma unroll
    for (int t = 0; t < 12; ++t) KEEP(a1[t]);
    f32x16 acc = zero16();
#pragma unroll
    for (int t = 0; t < 12; ++t)
      acc = __builtin_amdgcn_mfma_f32_32x32x16_bf16(a0[t], bfr[t], acc, 0, 0, 0);
    // prefetch first K-half of next tile
    if (mt + 1 < 8) {
      const unsigned short* arn = ab + (size_t)(mt + 1) * 24 * 512;
#pragma unroll
      for (int t = 0; t < 12; ++t) a0[t] = *(const bf16x8*)(arn + t * 512);
#pragma unroll
      for (int t = 0; t < 12; ++t) KEEP(a0[t]);
    }
#pragma unroll
    for (int t = 0; t < 12; ++t)
      acc = __builtin_amdgcn_mfma_f32_32x32x16_bf16(a1[t], bfr[12 + t], acc, 0, 0, 0);
    const int mb = (w * 8 + mt) * 32 + hi4;
#pragma unroll
    for (int r = 0; r < 16; ++r) {
      const int m = mb + (r & 3) + 8 * (r >> 2);
      ins7(acc[r], m, s7, j7);
    }
  }

  // merge lane pairs (lane, lane^32) covering the same q-column
#pragma unroll
  for (int t = 0; t < 7; ++t) {
    float ov = __shfl_xor(s7[t], 32, 64);
    int   oi = __shfl_xor(j7[t], 32, 64);
    ins7(ov, oi, s7, j7);
  }
  if (lane < 32) {
#pragma unroll
    for (int t = 0; t < 7; ++t) { cval[w][lo][t] = s7[t]; cidx[w][lo][t] = j7[t]; }
  }
  __syncthreads();

  // final merge: 32 threads, one q each, scan 16 waves x 7 candidates
  if (tid < 32) {
    float fv[7]; int fi[7]; float fvm = -1e30f; int fpm = 0;
#pragma unroll
    for (int t = 0; t < 7; ++t) { fv[t] = -1e30f; fi[t] = 0; }
    for (int w2 = 0; w2 < 16; ++w2)
#pragma unroll
      for (int t = 0; t < 7; ++t)
        top7_insert(cval[w2][tid][t], cidx[w2][tid][t], fv, fi, fvm, fpm);
    // FORCE self (self-sim = 1 is always the reference max)
    const int q = q0 + tid;
    bool has = false;
#pragma unroll
    for (int t = 0; t < 7; ++t) has = has || (fi[t] == q);
    if (!has) {
      float mn = fv[0]; int mp = 0;
#pragma unroll
      for (int t = 1; t < 7; ++t)
        if (fv[t] < mn) { mn = fv[t]; mp = t; }
#pragma unroll
      for (int t = 0; t < 7; ++t)
        if (t == mp) fi[t] = q;
    }
    int* o = knn_out + ((size_t)b * NPTS + q) * 7;
#pragma unroll
    for (int t = 0; t < 7; ++t) o[t] = fi[t];
  }
}

// ---------------------------------------------------------------------------
// K3: code similarities -> fixed-max LSE (self logit = 10 dominates) +
// depth-Gaussian weighted sum. 16 waves, 8 tiles/wave.
// ---------------------------------------------------------------------------
__global__ __launch_bounds__(1024, 1) void lse_depth(const unsigned short* __restrict__ Csw,
                                                     const float* __restrict__ depth,
                                                     float* __restrict__ lse_out,
                                                     float* __restrict__ dpart) {
  __shared__ float lsep[16][32];
  __shared__ float depp[16];
  const int g = blockIdx.x;
  const int xcd = g & 7;
  const int b = xcd >> 2;
  const int qt = ((g >> 3) << 2) | (xcd & 3);
  const int q0 = qt * 32;
  const int tid = threadIdx.x;
  const int w = tid >> 6;                // 0..15
  const int lane = tid & 63;
  const int lo = lane & 31, hi4 = (lane >> 5) * 4;
  const unsigned short* Cb = Csw + (size_t)b * 128 * 6 * 512;
  const float* db = depth + b * NPTS;

  bf16x8 bfr[6];
  {
    const unsigned short* qb = Cb + ((size_t)qt * 6) * 512 + lane * 8;
#pragma unroll
    for (int t = 0; t < 6; ++t) bfr[t] = *(const bf16x8*)(qb + t * 512);
#pragma unroll
    for (int t = 0; t < 6; ++t) KEEP(bfr[t]);
  }
  const float dq = db[q0 + lo];
  float slse = 0.f, sdep = 0.f;

  const int mbase = w * 8 * 32;          // 8 tiles
  const unsigned short* ab = Cb + ((size_t)(w * 8) * 6) * 512 + lane * 8;

  bf16x8 a0[6], a1[6];
#pragma unroll
  for (int t = 0; t < 6; ++t) a0[t] = *(const bf16x8*)(ab + t * 512);
#pragma unroll
  for (int t = 0; t < 6; ++t) KEEP(a0[t]);

#define PROC3(A, MT)                                                           \
  {                                                                            \
    f32x16 acc = zero16();                                                     \
    _Pragma("unroll")                                                          \
    for (int t = 0; t < 6; ++t)                                                \
      acc = __builtin_amdgcn_mfma_f32_32x32x16_bf16(A[t], bfr[t], acc, 0, 0, 0); \
    float dvv[16];                                                             \
    _Pragma("unroll")                                                          \
    for (int k = 0; k < 4; ++k) {                                              \
      float4 dv = *(const float4*)(db + mbase + (MT) * 32 + hi4 + 8 * k);      \
      dvv[k * 4 + 0] = dv.x; dvv[k * 4 + 1] = dv.y;                            \
      dvv[k * 4 + 2] = dv.z; dvv[k * 4 + 3] = dv.w;                            \
    }                                                                          \
    _Pragma("unroll")                                                          \
    for (int r = 0; r < 16; ++r) {                                             \
      const float s = acc[r];                                                  \
      const float dd = dq - dvv[r];                                            \
      sdep += __expf(-2.f * dd * dd) * (1.f - s);                              \
      slse += __expf(fmaf(s, 10.f, -10.f));                                    \
    }                                                                          \
  }

  for (int mt = 0; mt < 8; mt += 2) {
    {
      const unsigned short* ar = ab + (size_t)(mt + 1) * 6 * 512;
#pragma unroll
      for (int t = 0; t < 6; ++t) a1[t] = *(const bf16x8*)(ar + t * 512);
#pragma unroll
      for (int t = 0; t < 6; ++t) KEEP(a1[t]);
    }
    PROC3(a0, mt)
    if (mt + 2 < 8) {
      const unsigned short* ar = ab + (size_t)(mt + 2) * 6 * 512;
#pragma unroll
      for (int t = 0; t < 6; ++t) a0[t] = *(const bf16x8*)(ar + t * 512);
#pragma unroll
      for (int t = 0; t < 6; ++t) KEEP(a0[t]);
    }
    PROC3(a1, mt + 1)
  }
#undef PROC3

  slse += __shfl_xor(slse, 32, 64);
  if (lane < 32) lsep[w][lo] = slse;
#pragma unroll
  for (int m = 1; m <= 32; m <<= 1) sdep += __shfl_xor(sdep, m, 64);
  if (lane == 0) depp[w] = sdep;
  __syncthreads();
  if (tid < 32) {
    float tot = 0.f;
#pragma unroll
    for (int w2 = 0; w2 < 16; ++w2) tot += lsep[w2][tid];
    lse_out[(size_t)b * NPTS + q0 + tid] = 10.f + __logf(tot);
  }
  if (tid == 32) {
    float d = 0.f;
#pragma unroll
    for (int w2 = 0; w2 < 16; ++w2) d += depp[w2];
    dpart[g] = d;
  }
}

// ---------------------------------------------------------------------------
// K4: positive-pair code similarity in FP32 from raw codes. One wave per row.
// ---------------------------------------------------------------------------
__global__ __launch_bounds__(64) void gather_pos(const float* __restrict__ codes,
                                                 const float* __restrict__ invc,
                                                 const int* __restrict__ knn,
                                                 float* __restrict__ gpart) {
  const int n = blockIdx.x;              // 0..8191 (global row)
  const int b = n >> 12;
  const int lane = threadIdx.x;
  const float* cn = codes + (size_t)n * 90;
  float2 a = make_float2(0.f, 0.f);
  if (lane < 45) a = *(const float2*)(cn + lane * 2);
  const float inva = invc[n];
  float ssum = 0.f;
  for (int k = 0; k < 7; ++k) {
    const int m = knn[(size_t)n * 7 + k];
    const float* cm = codes + ((size_t)(b << 12) + m) * 90;
    float2 bb = make_float2(0.f, 0.f);
    if (lane < 45) bb = *(const float2*)(cm + lane * 2);
    float p = fmaf(a.x, bb.x, a.y * bb.y);
#pragma unroll
    for (int w = 1; w <= 32; w <<= 1) p += __shfl_xor(p, w, 64);
    ssum += p * inva * invc[(b << 12) + m];
  }
  if (lane == 0) gpart[n] = ssum;
}

// ---------------------------------------------------------------------------
// K5: finalize -> (l_stego, l_depthg, total)
// ---------------------------------------------------------------------------
__global__ __launch_bounds__(256) void finalize(const float* __restrict__ lse,
                                                const float* __restrict__ gpart,
                                                const float* __restrict__ dpart,
                                                float* __restrict__ out) {
  const int tid = threadIdx.x;
  float s1 = 0.f, s2 = 0.f;
  for (int i = tid; i < 2 * NPTS; i += 256) { s1 += lse[i]; s2 += gpart[i]; }
  float s3 = dpart[tid];
  __shared__ float r1[256], r2[256], r3[256];
  r1[tid] = s1; r2[tid] = s2; r3[tid] = s3;
  __syncthreads();
  for (int s = 128; s > 0; s >>= 1) {
    if (tid < s) { r1[tid] += r1[tid + s]; r2[tid] += r2[tid + s]; r3[tid] += r3[tid + s]; }
    __syncthreads();
  }
  if (tid == 0) {
    const float l_st = (7.f * r1[0] - 10.f * r2[0]) / 57344.f;
    const float l_dp = r3[0] / 33554432.f;
    out[0] = l_st;
    out[1] = l_dp;
    out[2] = l_st + 0.3f * l_dp;
  }
}

// ---------------------------------------------------------------------------
extern "C" void kernel_launch(void* const* d_in, const int* in_sizes, int n_in,
                              void* d_out, int out_size, void* d_ws, size_t ws_size,
                              hipStream_t stream) {
  (void)in_sizes; (void)n_in; (void)out_size; (void)ws_size;
  const float* codes = (const float*)d_in[0];   // (B,N,90)
  const float* feats = (const float*)d_in[1];   // (B,N,384)
  const float* depth = (const float*)d_in[2];   // (B,N)
  float* out = (float*)d_out;

  char* ws = (char*)d_ws;
  float* invc  = (float*)ws;                         // 32768 B  @ 0
  float* lse   = (float*)(ws + 32768);               // 32768 B
  float* dpart = (float*)(ws + 65536);               // 1024 B
  float* gpart = (float*)(ws + 66560);               // 32768 B
  int*   knn   = (int*)(ws + 99328);                 // 229376 B
  unsigned short* Csw = (unsigned short*)(ws + 328704);   // 1572864 B
  unsigned short* Fsw = (unsigned short*)(ws + 1901568);  // 6291456 B (end 8193024)

  norm_cast<<<2 * NPTS, 64, 0, stream>>>(codes, feats, Fsw, Csw, invc);
  knn_mfma<<<256, 1024, 0, stream>>>(Fsw, knn);
  lse_depth<<<256, 1024, 0, stream>>>(Csw, depth, lse, dpart);
  gather_pos<<<2 * NPTS, 64, 0, stream>>>(codes, invc, knn, gpart);
  finalize<<<1, 256, 0, stream>>>(lse, gpart, dpart, out);
}

// Round 9
// 355.542 us; speedup vs baseline: 1.7937x; 1.7937x over previous
//
#include <hip/hip_runtime.h>
#include <math.h>

#define NPTS 4096

typedef __attribute__((ext_vector_type(8))) short bf16x8;
typedef __attribute__((ext_vector_type(16))) float f32x16;

// liveness pin: forbid rematerialization / load sinking (round-5 lesson)
#define KEEP(x) asm volatile("" : "+v"(x))

__device__ __forceinline__ f32x16 zero16() {
  f32x16 z;
#pragma unroll
  for (int i = 0; i < 16; ++i) z[i] = 0.f;
  return z;
}

// branchless sorted-descending top-7 insert: wave take-prob ~1 makes the
// branchy version pay its body every site + exec-mask overhead; this is
// 7 cmp + 26 cndmask, fully static indexing per rule #20
__device__ __forceinline__ void ins7(float v, int i, float* s, int* j) {
  bool c[7];
#pragma unroll
  for (int t = 0; t < 7; ++t) c[t] = v > s[t];
#pragma unroll
  for (int t = 6; t >= 1; --t) {   // t reads s[t-1] before iteration t-1 writes it
    s[t] = c[t] ? (c[t - 1] ? s[t - 1] : v) : s[t];
    j[t] = c[t] ? (c[t - 1] ? j[t - 1] : i) : j[t];
  }
  s[0] = c[0] ? v : s[0];
  j[0] = c[0] ? i : j[0];
}

// classic insert (used only in the once-per-block final merge)
__device__ __forceinline__ void top7_insert(float v, int i, float* v7, int* i7,
                                            float& vmin, int& pmin) {
  if (v > vmin) {
#pragma unroll
    for (int t = 0; t < 7; ++t)
      if (t == pmin) { v7[t] = v; i7[t] = i; }
    vmin = v7[0]; pmin = 0;
#pragma unroll
    for (int t = 1; t < 7; ++t)
      if (v7[t] < vmin) { vmin = v7[t]; pmin = t; }
  }
}

__device__ __forceinline__ unsigned bf16pack(float a, float b) {
  unsigned ua = __float_as_uint(a); ua = (ua + 0x7FFFu + ((ua >> 16) & 1u)) >> 16;
  unsigned ub = __float_as_uint(b); ub = (ub + 0x7FFFu + ((ub >> 16) & 1u)) >> 16;
  return ua | (ub << 16);
}

// ---------------------------------------------------------------------------
// K1: normalize + cast + write FRAGMENT-MAJOR layout.
// Fsw[b][mt][kc(24)][lane(64)][8elem]; Csw[b][mt][kc(6)][lane(64)][8elem]
// ---------------------------------------------------------------------------
__global__ __launch_bounds__(64) void norm_cast(const float* __restrict__ codes,
                                                const float* __restrict__ feats,
                                                unsigned short* __restrict__ Fsw,
                                                unsigned short* __restrict__ Csw,
                                                float* __restrict__ invc) {
  const int row = blockIdx.x;            // 0 .. 8191
  const int lane = threadIdx.x;
  const int b = row >> 12, mt = (row >> 5) & 127, rl = row & 31;

  const float* f = feats + (size_t)row * 384;
  float v[8];
  float ss = 0.f;
  if (lane < 48) {
    float4 p0 = *(const float4*)(f + lane * 8);
    float4 p1 = *(const float4*)(f + lane * 8 + 4);
    v[0] = p0.x; v[1] = p0.y; v[2] = p0.z; v[3] = p0.w;
    v[4] = p1.x; v[5] = p1.y; v[6] = p1.z; v[7] = p1.w;
#pragma unroll
    for (int e = 0; e < 8; ++e) ss = fmaf(v[e], v[e], ss);
  }
#pragma unroll
  for (int m = 1; m <= 32; m <<= 1) ss += __shfl_xor(ss, m, 64);
  const float inv = rsqrtf(ss + 1e-8f);
  if (lane < 48) {
    uint4 o;
    o.x = bf16pack(v[0] * inv, v[1] * inv);
    o.y = bf16pack(v[2] * inv, v[3] * inv);
    o.z = bf16pack(v[4] * inv, v[5] * inv);
    o.w = bf16pack(v[6] * inv, v[7] * inv);
    const int kc = lane >> 1, hs = lane & 1;
    *(uint4*)(Fsw + (((size_t)(b * 128 + mt) * 24 + kc) << 9) + (hs * 32 + rl) * 8) = o;
  }

  const float* c = codes + (size_t)row * 90;
  float cv[8];
#pragma unroll
  for (int e = 0; e < 8; ++e) cv[e] = 0.f;
  if (lane < 11) {
    float4 p0 = *(const float4*)(c + lane * 8);
    float4 p1 = *(const float4*)(c + lane * 8 + 4);
    cv[0] = p0.x; cv[1] = p0.y; cv[2] = p0.z; cv[3] = p0.w;
    cv[4] = p1.x; cv[5] = p1.y; cv[6] = p1.z; cv[7] = p1.w;
  } else if (lane == 11) {
    cv[0] = c[88]; cv[1] = c[89];
  }
  float cs = 0.f;
#pragma unroll
  for (int e = 0; e < 8; ++e) cs = fmaf(cv[e], cv[e], cs);
#pragma unroll
  for (int m = 1; m <= 32; m <<= 1) cs += __shfl_xor(cs, m, 64);
  const float cinv = rsqrtf(cs + 1e-8f);
  if (lane < 12) {
    uint4 o;
    o.x = bf16pack(cv[0] * cinv, cv[1] * cinv);
    o.y = bf16pack(cv[2] * cinv, cv[3] * cinv);
    o.z = bf16pack(cv[4] * cinv, cv[5] * cinv);
    o.w = bf16pack(cv[6] * cinv, cv[7] * cinv);
    const int kc = lane >> 1, hs = lane & 1;
    *(uint4*)(Csw + (((size_t)(b * 128 + mt) * 6 + kc) << 9) + (hs * 32 + rl) * 8) = o;
  }
  if (lane == 0) invc[row] = cinv;
}

// ---------------------------------------------------------------------------
// K2: feature similarities via 32x32x16 bf16 MFMA (swapped: D[m][q]) + top-7.
// 768 thr / 12 waves (3 waves/SIMD — the max the ~116-170 VGPR live set
// permits; round-8 lesson: 16 waves forced VGPR=64 -> 857 MB spill).
// Wave w sweeps m-tiles [w*128/12, (w+1)*128/12) (10-11 tiles).
// ---------------------------------------------------------------------------
__global__ __launch_bounds__(768, 3) void knn_mfma(const unsigned short* __restrict__ Fsw,
                                                   int* __restrict__ knn_out) {
  __shared__ float cval[12][32][7];
  __shared__ int   cidx[12][32][7];
  const int g = blockIdx.x;              // 0..255
  const int b = g & 1;
  const int qt = g >> 1;                 // q-tile 0..127
  const int q0 = qt * 32;
  const int tid = threadIdx.x;
  const int w = tid >> 6;                // 0..11
  const int lane = tid & 63;
  const int lo = lane & 31, hi4 = (lane >> 5) * 4;
  const unsigned short* Fb = Fsw + (size_t)b * 128 * 24 * 512;

  bf16x8 bfr[24];
  {
    const unsigned short* qb = Fb + ((size_t)qt * 24) * 512 + lane * 8;
#pragma unroll
    for (int t = 0; t < 24; ++t) bfr[t] = *(const bf16x8*)(qb + t * 512);
#pragma unroll
    for (int t = 0; t < 24; ++t) KEEP(bfr[t]);
  }
  float s7[7]; int j7[7];
#pragma unroll
  for (int t = 0; t < 7; ++t) { s7[t] = -1e30f; j7[t] = 0; }

  const int ts = (w * 128) / 12, te = ((w + 1) * 128) / 12;   // 10-11 tiles
  const unsigned short* ab = Fb + (size_t)0 + lane * 8;

  bf16x8 a0[12], a1[12];
  {
    const unsigned short* ar = ab + (size_t)ts * 24 * 512;
#pragma unroll
    for (int t = 0; t < 12; ++t) a0[t] = *(const bf16x8*)(ar + t * 512);
#pragma unroll
    for (int t = 0; t < 12; ++t) KEEP(a0[t]);
  }

  for (int mt = ts; mt < te; ++mt) {
    const unsigned short* art = ab + (size_t)mt * 24 * 512;
    // prefetch second K-half of this tile
#pragma unroll
    for (int t = 0; t < 12; ++t) a1[t] = *(const bf16x8*)(art + (12 + t) * 512);
#pragma unroll
    for (int t = 0; t < 12; ++t) KEEP(a1[t]);
    f32x16 acc = zero16();
#pragma unroll
    for (int t = 0; t < 12; ++t)
      acc = __builtin_amdgcn_mfma_f32_32x32x16_bf16(a0[t], bfr[t], acc, 0, 0, 0);
    // prefetch first K-half of next tile
    if (mt + 1 < te) {
      const unsigned short* arn = ab + (size_t)(mt + 1) * 24 * 512;
#pragma unroll
      for (int t = 0; t < 12; ++t) a0[t] = *(const bf16x8*)(arn + t * 512);
#pragma unroll
      for (int t = 0; t < 12; ++t) KEEP(a0[t]);
    }
#pragma unroll
    for (int t = 0; t < 12; ++t)
      acc = __builtin_amdgcn_mfma_f32_32x32x16_bf16(a1[t], bfr[12 + t], acc, 0, 0, 0);
    const int mb = mt * 32 + hi4;
#pragma unroll
    for (int r = 0; r < 16; ++r) {
      const int m = mb + (r & 3) + 8 * (r >> 2);
      ins7(acc[r], m, s7, j7);
    }
  }

  // merge lane pairs (lane, lane^32) covering the same q-column
#pragma unroll
  for (int t = 0; t < 7; ++t) {
    float ov = __shfl_xor(s7[t], 32, 64);
    int   oi = __shfl_xor(j7[t], 32, 64);
    ins7(ov, oi, s7, j7);
  }
  if (lane < 32) {
#pragma unroll
    for (int t = 0; t < 7; ++t) { cval[w][lo][t] = s7[t]; cidx[w][lo][t] = j7[t]; }
  }
  __syncthreads();

  // final merge: 32 threads, one q each, scan 12 waves x 7 candidates
  if (tid < 32) {
    float fv[7]; int fi[7]; float fvm = -1e30f; int fpm = 0;
#pragma unroll
    for (int t = 0; t < 7; ++t) { fv[t] = -1e30f; fi[t] = 0; }
    for (int w2 = 0; w2 < 12; ++w2)
#pragma unroll
      for (int t = 0; t < 7; ++t)
        top7_insert(cval[w2][tid][t], cidx[w2][tid][t], fv, fi, fvm, fpm);
    // FORCE self (self-sim = 1 is always the reference max)
    const int q = q0 + tid;
    bool has = false;
#pragma unroll
    for (int t = 0; t < 7; ++t) has = has || (fi[t] == q);
    if (!has) {
      float mn = fv[0]; int mp = 0;
#pragma unroll
      for (int t = 1; t < 7; ++t)
        if (fv[t] < mn) { mn = fv[t]; mp = t; }
#pragma unroll
      for (int t = 0; t < 7; ++t)
        if (t == mp) fi[t] = q;
    }
    int* o = knn_out + ((size_t)b * NPTS + q) * 7;
#pragma unroll
    for (int t = 0; t < 7; ++t) o[t] = fi[t];
  }
}

// ---------------------------------------------------------------------------
// K3: code similarities -> fixed-max LSE (self logit = 10 dominates) +
// depth-Gaussian weighted sum. 12 waves, 10-11 tiles each.
// ---------------------------------------------------------------------------
__global__ __launch_bounds__(768, 3) void lse_depth(const unsigned short* __restrict__ Csw,
                                                    const float* __restrict__ depth,
                                                    float* __restrict__ lse_out,
                                                    float* __restrict__ dpart) {
  __shared__ float lsep[12][32];
  __shared__ float depp[12];
  const int g = blockIdx.x;
  const int b = g & 1;
  const int qt = g >> 1;
  const int q0 = qt * 32;
  const int tid = threadIdx.x;
  const int w = tid >> 6;                // 0..11
  const int lane = tid & 63;
  const int lo = lane & 31, hi4 = (lane >> 5) * 4;
  const unsigned short* Cb = Csw + (size_t)b * 128 * 6 * 512;
  const float* db = depth + b * NPTS;

  bf16x8 bfr[6];
  {
    const unsigned short* qb = Cb + ((size_t)qt * 6) * 512 + lane * 8;
#pragma unroll
    for (int t = 0; t < 6; ++t) bfr[t] = *(const bf16x8*)(qb + t * 512);
#pragma unroll
    for (int t = 0; t < 6; ++t) KEEP(bfr[t]);
  }
  const float dq = db[q0 + lo];
  float slse = 0.f, sdep = 0.f;

  const int ts = (w * 128) / 12, te = ((w + 1) * 128) / 12;
  const unsigned short* ab = Cb + lane * 8;

  bf16x8 a0[6], a1[6];
  {
    const unsigned short* ar = ab + (size_t)ts * 6 * 512;
#pragma unroll
    for (int t = 0; t < 6; ++t) a0[t] = *(const bf16x8*)(ar + t * 512);
#pragma unroll
    for (int t = 0; t < 6; ++t) KEEP(a0[t]);
  }

#define PROC3(A, MT)                                                           \
  {                                                                            \
    f32x16 acc = zero16();                                                     \
    _Pragma("unroll")                                                          \
    for (int t = 0; t < 6; ++t)                                                \
      acc = __builtin_amdgcn_mfma_f32_32x32x16_bf16(A[t], bfr[t], acc, 0, 0, 0); \
    float dvv[16];                                                             \
    _Pragma("unroll")                                                          \
    for (int k = 0; k < 4; ++k) {                                              \
      float4 dv = *(const float4*)(db + (MT) * 32 + hi4 + 8 * k);              \
      dvv[k * 4 + 0] = dv.x; dvv[k * 4 + 1] = dv.y;                            \
      dvv[k * 4 + 2] = dv.z; dvv[k * 4 + 3] = dv.w;                            \
    }                                                                          \
    _Pragma("unroll")                                                          \
    for (int r = 0; r < 16; ++r) {                                             \
      const float s = acc[r];                                                  \
      const float dd = dq - dvv[r];                                            \
      sdep += __expf(-2.f * dd * dd) * (1.f - s);                              \
      slse += __expf(fmaf(s, 10.f, -10.f));                                    \
    }                                                                          \
  }

  int mt = ts;
  for (; mt + 2 <= te; mt += 2) {
    {
      const unsigned short* ar = ab + (size_t)(mt + 1) * 6 * 512;
#pragma unroll
      for (int t = 0; t < 6; ++t) a1[t] = *(const bf16x8*)(ar + t * 512);
#pragma unroll
      for (int t = 0; t < 6; ++t) KEEP(a1[t]);
    }
    PROC3(a0, mt)
    if (mt + 2 < te) {
      const unsigned short* ar = ab + (size_t)(mt + 2) * 6 * 512;
#pragma unroll
      for (int t = 0; t < 6; ++t) a0[t] = *(const bf16x8*)(ar + t * 512);
#pragma unroll
      for (int t = 0; t < 6; ++t) KEEP(a0[t]);
    }
    PROC3(a1, mt + 1)
  }
  if (mt < te) {                          // odd tail (a0 holds tile te-1)
    PROC3(a0, mt)
  }
#undef PROC3

  slse += __shfl_xor(slse, 32, 64);
  if (lane < 32) lsep[w][lo] = slse;
#pragma unroll
  for (int m = 1; m <= 32; m <<= 1) sdep += __shfl_xor(sdep, m, 64);
  if (lane == 0) depp[w] = sdep;
  __syncthreads();
  if (tid < 32) {
    float tot = 0.f;
#pragma unroll
    for (int w2 = 0; w2 < 12; ++w2) tot += lsep[w2][tid];
    lse_out[(size_t)b * NPTS + q0 + tid] = 10.f + __logf(tot);
  }
  if (tid == 32) {
    float d = 0.f;
#pragma unroll
    for (int w2 = 0; w2 < 12; ++w2) d += depp[w2];
    dpart[g] = d;
  }
}

// ---------------------------------------------------------------------------
// K4: positive-pair code similarity in FP32 from raw codes. One wave per row.
// ---------------------------------------------------------------------------
__global__ __launch_bounds__(64) void gather_pos(const float* __restrict__ codes,
                                                 const float* __restrict__ invc,
                                                 const int* __restrict__ knn,
                                                 float* __restrict__ gpart) {
  const int n = blockIdx.x;              // 0..8191 (global row)
  const int b = n >> 12;
  const int lane = threadIdx.x;
  const float* cn = codes + (size_t)n * 90;
  float2 a = make_float2(0.f, 0.f);
  if (lane < 45) a = *(const float2*)(cn + lane * 2);
  const float inva = invc[n];
  float ssum = 0.f;
  for (int k = 0; k < 7; ++k) {
    const int m = knn[(size_t)n * 7 + k];
    const float* cm = codes + ((size_t)(b << 12) + m) * 90;
    float2 bb = make_float2(0.f, 0.f);
    if (lane < 45) bb = *(const float2*)(cm + lane * 2);
    float p = fmaf(a.x, bb.x, a.y * bb.y);
#pragma unroll
    for (int w = 1; w <= 32; w <<= 1) p += __shfl_xor(p, w, 64);
    ssum += p * inva * invc[(b << 12) + m];
  }
  if (lane == 0) gpart[n] = ssum;
}

// ---------------------------------------------------------------------------
// K5: finalize -> (l_stego, l_depthg, total)
// ---------------------------------------------------------------------------
__global__ __launch_bounds__(256) void finalize(const float* __restrict__ lse,
                                                const float* __restrict__ gpart,
                                                const float* __restrict__ dpart,
                                                float* __restrict__ out) {
  const int tid = threadIdx.x;
  float s1 = 0.f, s2 = 0.f;
  for (int i = tid; i < 2 * NPTS; i += 256) { s1 += lse[i]; s2 += gpart[i]; }
  float s3 = dpart[tid];
  __shared__ float r1[256], r2[256], r3[256];
  r1[tid] = s1; r2[tid] = s2; r3[tid] = s3;
  __syncthreads();
  for (int s = 128; s > 0; s >>= 1) {
    if (tid < s) { r1[tid] += r1[tid + s]; r2[tid] += r2[tid + s]; r3[tid] += r3[tid + s]; }
    __syncthreads();
  }
  if (tid == 0) {
    const float l_st = (7.f * r1[0] - 10.f * r2[0]) / 57344.f;
    const float l_dp = r3[0] / 33554432.f;
    out[0] = l_st;
    out[1] = l_dp;
    out[2] = l_st + 0.3f * l_dp;
  }
}

// ---------------------------------------------------------------------------
extern "C" void kernel_launch(void* const* d_in, const int* in_sizes, int n_in,
                              void* d_out, int out_size, void* d_ws, size_t ws_size,
                              hipStream_t stream) {
  (void)in_sizes; (void)n_in; (void)out_size; (void)ws_size;
  const float* codes = (const float*)d_in[0];   // (B,N,90)
  const float* feats = (const float*)d_in[1];   // (B,N,384)
  const float* depth = (const float*)d_in[2];   // (B,N)
  float* out = (float*)d_out;

  char* ws = (char*)d_ws;
  float* invc  = (float*)ws;                         // 32768 B  @ 0
  float* lse   = (float*)(ws + 32768);               // 32768 B
  float* dpart = (float*)(ws + 65536);               // 1024 B
  float* gpart = (float*)(ws + 66560);               // 32768 B
  int*   knn   = (int*)(ws + 99328);                 // 229376 B
  unsigned short* Csw = (unsigned short*)(ws + 328704);   // 1572864 B
  unsigned short* Fsw = (unsigned short*)(ws + 1901568);  // 6291456 B (end 8193024)

  norm_cast<<<2 * NPTS, 64, 0, stream>>>(codes, feats, Fsw, Csw, invc);
  knn_mfma<<<256, 768, 0, stream>>>(Fsw, knn);
  lse_depth<<<256, 768, 0, stream>>>(Csw, depth, lse, dpart);
  gather_pos<<<2 * NPTS, 64, 0, stream>>>(codes, invc, knn, gpart);
  finalize<<<1, 256, 0, stream>>>(lse, gpart, dpart, out);
}

// Round 10
// 97.860 us; speedup vs baseline: 6.5169x; 3.6332x over previous
//
#include <hip/hip_runtime.h>
#include <math.h>

#define NPTS 4096

typedef __attribute__((ext_vector_type(8))) short bf16x8;
typedef __attribute__((ext_vector_type(16))) float f32x16;

// liveness pin: forbid rematerialization / load sinking (round-5 lesson)
#define KEEP(x) asm volatile("" : "+v"(x))

__device__ __forceinline__ f32x16 zero16() {
  f32x16 z;
#pragma unroll
  for (int i = 0; i < 16; ++i) z[i] = 0.f;
  return z;
}

// monotonic sortable key (ascending with float value) with 12-bit m index
// embedded in the low mantissa bits (clearing them perturbs the compared
// value by ~2^-12 relative -- far below the bf16 noise already tolerated).
__device__ __forceinline__ unsigned packkey(float x, int m) {
  unsigned u = __float_as_uint(x);
  unsigned key = u ^ ((unsigned)((int)u >> 31) | 0x80000000u);
  return (key & 0xFFFFF000u) | (unsigned)m;
}

// cascade insert into sorted-descending 7-array: 7 umax + 7 umin, no branches
__device__ __forceinline__ void cas7(unsigned v, unsigned* s) {
#pragma unroll
  for (int t = 0; t < 7; ++t) {
    const unsigned hi = s[t] >= v ? s[t] : v;
    const unsigned lo = s[t] >= v ? v : s[t];
    s[t] = hi;
    v = lo;
  }
}

__device__ __forceinline__ unsigned bf16pack(float a, float b) {
  unsigned ua = __float_as_uint(a); ua = (ua + 0x7FFFu + ((ua >> 16) & 1u)) >> 16;
  unsigned ub = __float_as_uint(b); ub = (ub + 0x7FFFu + ((ub >> 16) & 1u)) >> 16;
  return ua | (ub << 16);
}

// ---------------------------------------------------------------------------
// K1a: normalize features -> fragment-major bf16 Fsw[b][mt][kc(24)][lane(64)][8]
// ---------------------------------------------------------------------------
__global__ __launch_bounds__(64) void norm_f(const float* __restrict__ feats,
                                             unsigned short* __restrict__ Fsw) {
  const int row = blockIdx.x;            // 0 .. 8191
  const int lane = threadIdx.x;
  const int b = row >> 12, mt = (row >> 5) & 127, rl = row & 31;

  const float* f = feats + (size_t)row * 384;
  float v[8];
  float ss = 0.f;
  if (lane < 48) {
    float4 p0 = *(const float4*)(f + lane * 8);
    float4 p1 = *(const float4*)(f + lane * 8 + 4);
    v[0] = p0.x; v[1] = p0.y; v[2] = p0.z; v[3] = p0.w;
    v[4] = p1.x; v[5] = p1.y; v[6] = p1.z; v[7] = p1.w;
#pragma unroll
    for (int e = 0; e < 8; ++e) ss = fmaf(v[e], v[e], ss);
  }
#pragma unroll
  for (int m = 1; m <= 32; m <<= 1) ss += __shfl_xor(ss, m, 64);
  const float inv = rsqrtf(ss + 1e-8f);
  if (lane < 48) {
    uint4 o;
    o.x = bf16pack(v[0] * inv, v[1] * inv);
    o.y = bf16pack(v[2] * inv, v[3] * inv);
    o.z = bf16pack(v[4] * inv, v[5] * inv);
    o.w = bf16pack(v[6] * inv, v[7] * inv);
    const int kc = lane >> 1, hs = lane & 1;
    *(uint4*)(Fsw + (((size_t)(b * 128 + mt) * 24 + kc) << 9) + (hs * 32 + rl) * 8) = o;
  }
}

// ---------------------------------------------------------------------------
// K1b: normalize codes -> Csw[b][mt][kc(6)][lane(64)][8] (zero-padded to 96)
// + fp32 inverse norms. Runs AFTER knn_mfma: Csw overlays the dead Fsw region.
// ---------------------------------------------------------------------------
__global__ __launch_bounds__(64) void norm_c(const float* __restrict__ codes,
                                             unsigned short* __restrict__ Csw,
                                             float* __restrict__ invc) {
  const int row = blockIdx.x;
  const int lane = threadIdx.x;
  const int b = row >> 12, mt = (row >> 5) & 127, rl = row & 31;

  const float* c = codes + (size_t)row * 90;
  float cv[8];
#pragma unroll
  for (int e = 0; e < 8; ++e) cv[e] = 0.f;
  if (lane < 11) {
    float4 p0 = *(const float4*)(c + lane * 8);
    float4 p1 = *(const float4*)(c + lane * 8 + 4);
    cv[0] = p0.x; cv[1] = p0.y; cv[2] = p0.z; cv[3] = p0.w;
    cv[4] = p1.x; cv[5] = p1.y; cv[6] = p1.z; cv[7] = p1.w;
  } else if (lane == 11) {
    cv[0] = c[88]; cv[1] = c[89];
  }
  float cs = 0.f;
#pragma unroll
  for (int e = 0; e < 8; ++e) cs = fmaf(cv[e], cv[e], cs);
#pragma unroll
  for (int m = 1; m <= 32; m <<= 1) cs += __shfl_xor(cs, m, 64);
  const float cinv = rsqrtf(cs + 1e-8f);
  if (lane < 12) {
    uint4 o;
    o.x = bf16pack(cv[0] * cinv, cv[1] * cinv);
    o.y = bf16pack(cv[2] * cinv, cv[3] * cinv);
    o.z = bf16pack(cv[4] * cinv, cv[5] * cinv);
    o.w = bf16pack(cv[6] * cinv, cv[7] * cinv);
    const int kc = lane >> 1, hs = lane & 1;
    *(uint4*)(Csw + (((size_t)(b * 128 + mt) * 6 + kc) << 9) + (hs * 32 + rl) * 8) = o;
  }
  if (lane == 0) invc[row] = cinv;
}

// ---------------------------------------------------------------------------
// K2: feature similarities via 32x32x16 bf16 MFMA (swapped: D[m][q]) + top-7.
// Grid 512 = qt(128) x half(2) x b(2): each block sweeps one m-HALF (64 tiles,
// 8 tiles/wave). 512-thr blocks, (512,1) -- the ONLY proven-stable config
// (rounds 8/9: any other launch_bounds triggered catastrophic spill).
// VGPR=116 <= 128 -> 2 blocks/CU co-reside = 4 waves/SIMD.
// Per-q top-7 packed keys written to cand; cross-half merge fused into gather.
// ---------------------------------------------------------------------------
__global__ __launch_bounds__(512, 1) void knn_mfma(const unsigned short* __restrict__ Fsw,
                                                   unsigned* __restrict__ cand) {
  __shared__ unsigned ckey[8][32][7];
  const int g = blockIdx.x;              // 0..511
  const int b = g & 1;
  const int h = (g >> 1) & 1;            // m-half
  const int qt = g >> 2;                 // q-tile 0..127
  const int q0 = qt * 32;
  const int tid = threadIdx.x;
  const int w = tid >> 6;                // 0..7
  const int lane = tid & 63;
  const int lo = lane & 31, hi4 = (lane >> 5) * 4;
  const unsigned short* Fb = Fsw + (size_t)b * 128 * 24 * 512;

  bf16x8 bfr[24];
  {
    const unsigned short* qb = Fb + ((size_t)qt * 24) * 512 + lane * 8;
#pragma unroll
    for (int t = 0; t < 24; ++t) bfr[t] = *(const bf16x8*)(qb + t * 512);
#pragma unroll
    for (int t = 0; t < 24; ++t) KEEP(bfr[t]);
  }
  unsigned s7[7];
#pragma unroll
  for (int t = 0; t < 7; ++t) s7[t] = 0u;

  const int t0 = h * 64 + w * 8;         // this wave's first global tile
  const unsigned short* ab = Fb + ((size_t)t0 * 24) * 512 + lane * 8;

  bf16x8 a0[12], a1[12];
#pragma unroll
  for (int t = 0; t < 12; ++t) a0[t] = *(const bf16x8*)(ab + t * 512);
#pragma unroll
  for (int t = 0; t < 12; ++t) KEEP(a0[t]);

  for (int mt = 0; mt < 8; ++mt) {
    const unsigned short* art = ab + (size_t)mt * 24 * 512;
#pragma unroll
    for (int t = 0; t < 12; ++t) a1[t] = *(const bf16x8*)(art + (12 + t) * 512);
#pragma unroll
    for (int t = 0; t < 12; ++t) KEEP(a1[t]);
    f32x16 acc = zero16();
#pragma unroll
    for (int t = 0; t < 12; ++t)
      acc = __builtin_amdgcn_mfma_f32_32x32x16_bf16(a0[t], bfr[t], acc, 0, 0, 0);
    if (mt + 1 < 8) {
      const unsigned short* arn = ab + (size_t)(mt + 1) * 24 * 512;
#pragma unroll
      for (int t = 0; t < 12; ++t) a0[t] = *(const bf16x8*)(arn + t * 512);
#pragma unroll
      for (int t = 0; t < 12; ++t) KEEP(a0[t]);
    }
#pragma unroll
    for (int t = 0; t < 12; ++t)
      acc = __builtin_amdgcn_mfma_f32_32x32x16_bf16(a1[t], bfr[12 + t], acc, 0, 0, 0);
    const int mb = (t0 + mt) * 32 + hi4;
#pragma unroll
    for (int r = 0; r < 16; ++r) {
      const int m = mb + (r & 3) + 8 * (r >> 2);
      cas7(packkey(acc[r], m), s7);
    }
  }

  // merge lane pairs (lane, lane^32) covering the same q-column
#pragma unroll
  for (int t = 0; t < 7; ++t) {
    const unsigned ov = (unsigned)__shfl_xor((int)s7[t], 32, 64);
    cas7(ov, s7);
  }
  if (lane < 32) {
#pragma unroll
    for (int t = 0; t < 7; ++t) ckey[w][lo][t] = s7[t];
  }
  __syncthreads();

  // block merge: 32 threads, one q each, scan 8 waves x 7 keys -> cand
  if (tid < 32) {
    unsigned fs[7];
#pragma unroll
    for (int t = 0; t < 7; ++t) fs[t] = 0u;
    for (int w2 = 0; w2 < 8; ++w2)
#pragma unroll
      for (int t = 0; t < 7; ++t) cas7(ckey[w2][tid][t], fs);
    unsigned* o = cand + ((size_t)((h * 2 + b) * NPTS) + q0 + tid) * 7;
#pragma unroll
    for (int t = 0; t < 7; ++t) o[t] = fs[t];
  }
}

// ---------------------------------------------------------------------------
// K3: code similarities -> partial exp-sums (fixed shift 10 = self logit) +
// depth-Gaussian weighted sum. Same grid-512 m-half split.
// ---------------------------------------------------------------------------
__global__ __launch_bounds__(512, 1) void lse_depth(const unsigned short* __restrict__ Csw,
                                                    const float* __restrict__ depth,
                                                    float* __restrict__ slse_part,
                                                    float* __restrict__ dpart) {
  __shared__ float lsep[8][32];
  __shared__ float depp[8];
  const int g = blockIdx.x;              // 0..511
  const int b = g & 1;
  const int h = (g >> 1) & 1;
  const int qt = g >> 2;
  const int q0 = qt * 32;
  const int tid = threadIdx.x;
  const int w = tid >> 6;
  const int lane = tid & 63;
  const int lo = lane & 31, hi4 = (lane >> 5) * 4;
  const unsigned short* Cb = Csw + (size_t)b * 128 * 6 * 512;
  const float* db = depth + b * NPTS;

  bf16x8 bfr[6];
  {
    const unsigned short* qb = Cb + ((size_t)qt * 6) * 512 + lane * 8;
#pragma unroll
    for (int t = 0; t < 6; ++t) bfr[t] = *(const bf16x8*)(qb + t * 512);
#pragma unroll
    for (int t = 0; t < 6; ++t) KEEP(bfr[t]);
  }
  const float dq = db[q0 + lo];
  float slse = 0.f, sdep = 0.f;

  const int t0 = h * 64 + w * 8;
  const unsigned short* ab = Cb + ((size_t)t0 * 6) * 512 + lane * 8;

  bf16x8 a0[6], a1[6];
#pragma unroll
  for (int t = 0; t < 6; ++t) a0[t] = *(const bf16x8*)(ab + t * 512);
#pragma unroll
  for (int t = 0; t < 6; ++t) KEEP(a0[t]);

#define PROC3(A, GT)                                                           \
  {                                                                            \
    f32x16 acc = zero16();                                                     \
    _Pragma("unroll")                                                          \
    for (int t = 0; t < 6; ++t)                                                \
      acc = __builtin_amdgcn_mfma_f32_32x32x16_bf16(A[t], bfr[t], acc, 0, 0, 0); \
    float dvv[16];                                                             \
    _Pragma("unroll")                                                          \
    for (int k = 0; k < 4; ++k) {                                              \
      float4 dv = *(const float4*)(db + (GT) * 32 + hi4 + 8 * k);              \
      dvv[k * 4 + 0] = dv.x; dvv[k * 4 + 1] = dv.y;                            \
      dvv[k * 4 + 2] = dv.z; dvv[k * 4 + 3] = dv.w;                            \
    }                                                                          \
    _Pragma("unroll")                                                          \
    for (int r = 0; r < 16; ++r) {                                             \
      const float s = acc[r];                                                  \
      const float dd = dq - dvv[r];                                            \
      sdep += __expf(-2.f * dd * dd) * (1.f - s);                              \
      slse += __expf(fmaf(s, 10.f, -10.f));                                    \
    }                                                                          \
  }

  for (int mt = 0; mt < 8; mt += 2) {
    {
      const unsigned short* ar = ab + (size_t)(mt + 1) * 6 * 512;
#pragma unroll
      for (int t = 0; t < 6; ++t) a1[t] = *(const bf16x8*)(ar + t * 512);
#pragma unroll
      for (int t = 0; t < 6; ++t) KEEP(a1[t]);
    }
    PROC3(a0, t0 + mt)
    if (mt + 2 < 8) {
      const unsigned short* ar = ab + (size_t)(mt + 2) * 6 * 512;
#pragma unroll
      for (int t = 0; t < 6; ++t) a0[t] = *(const bf16x8*)(ar + t * 512);
#pragma unroll
      for (int t = 0; t < 6; ++t) KEEP(a0[t]);
    }
    PROC3(a1, t0 + mt + 1)
  }
#undef PROC3

  slse += __shfl_xor(slse, 32, 64);
  if (lane < 32) lsep[w][lo] = slse;
#pragma unroll
  for (int m = 1; m <= 32; m <<= 1) sdep += __shfl_xor(sdep, m, 64);
  if (lane == 0) depp[w] = sdep;
  __syncthreads();
  if (tid < 32) {
    float tot = 0.f;
#pragma unroll
    for (int w2 = 0; w2 < 8; ++w2) tot += lsep[w2][tid];
    slse_part[(size_t)((h * 2 + b) * NPTS) + q0 + tid] = tot;   // raw exp-sum
  }
  if (tid == 32) {
    float d = 0.f;
#pragma unroll
    for (int w2 = 0; w2 < 8; ++w2) d += depp[w2];
    dpart[g] = d;
  }
}

// ---------------------------------------------------------------------------
// K4: merge the two half-candidate lists, force self, then 7 positive-pair
// code dots in FP32 from raw codes. One wave per row.
// ---------------------------------------------------------------------------
__global__ __launch_bounds__(64) void gather_pos(const float* __restrict__ codes,
                                                 const float* __restrict__ invc,
                                                 const unsigned* __restrict__ cand,
                                                 float* __restrict__ gpart) {
  const int n = blockIdx.x;              // 0..8191 (global row)
  const int b = n >> 12, q = n & 4095;
  const int lane = threadIdx.x;

  // merge 2 x 7 packed keys (all lanes redundantly; broadcast loads)
  unsigned s[7];
#pragma unroll
  for (int t = 0; t < 7; ++t) s[t] = 0u;
  const unsigned* c0 = cand + ((size_t)(b * NPTS) + q) * 7;
  const unsigned* c1 = cand + ((size_t)((2 + b) * NPTS) + q) * 7;
#pragma unroll
  for (int t = 0; t < 7; ++t) cas7(c0[t], s);
#pragma unroll
  for (int t = 0; t < 7; ++t) cas7(c1[t], s);
  // FORCE self (self-sim = 1 is always the reference max)
  bool has = false;
#pragma unroll
  for (int t = 0; t < 7; ++t) has = has || ((s[t] & 4095u) == (unsigned)q);
  if (!has) s[6] = (unsigned)q;

  const float* cn = codes + (size_t)n * 90;
  float2 a = make_float2(0.f, 0.f);
  if (lane < 45) a = *(const float2*)(cn + lane * 2);
  const float inva = invc[n];
  float ssum = 0.f;
#pragma unroll
  for (int k = 0; k < 7; ++k) {
    const int m = (int)(s[k] & 4095u);
    const float* cm = codes + ((size_t)(b << 12) + m) * 90;
    float2 bb = make_float2(0.f, 0.f);
    if (lane < 45) bb = *(const float2*)(cm + lane * 2);
    float p = fmaf(a.x, bb.x, a.y * bb.y);
#pragma unroll
    for (int w = 1; w <= 32; w <<= 1) p += __shfl_xor(p, w, 64);
    ssum += p * inva * invc[(b << 12) + m];
  }
  if (lane == 0) gpart[n] = ssum;
}

// ---------------------------------------------------------------------------
// K5: finalize -> (l_stego, l_depthg, total). Log of merged exp-sums here.
// ---------------------------------------------------------------------------
__global__ __launch_bounds__(256) void finalize(const float* __restrict__ slse_part,
                                                const float* __restrict__ gpart,
                                                const float* __restrict__ dpart,
                                                float* __restrict__ out) {
  const int tid = threadIdx.x;
  float s1 = 0.f, s2 = 0.f;
  for (int n = tid; n < 2 * NPTS; n += 256) {
    const int b = n >> 12, q = n & 4095;
    const float p = slse_part[b * NPTS + q] + slse_part[(2 + b) * NPTS + q];
    s1 += 10.f + __logf(p);
    s2 += gpart[n];
  }
  float s3 = dpart[tid] + dpart[tid + 256];
  __shared__ float r1[256], r2[256], r3[256];
  r1[tid] = s1; r2[tid] = s2; r3[tid] = s3;
  __syncthreads();
  for (int s = 128; s > 0; s >>= 1) {
    if (tid < s) { r1[tid] += r1[tid + s]; r2[tid] += r2[tid + s]; r3[tid] += r3[tid + s]; }
    __syncthreads();
  }
  if (tid == 0) {
    const float l_st = (7.f * r1[0] - 10.f * r2[0]) / 57344.f;
    const float l_dp = r3[0] / 33554432.f;
    out[0] = l_st;
    out[1] = l_dp;
    out[2] = l_st + 0.3f * l_dp;
  }
}

// ---------------------------------------------------------------------------
// ws layout (peak 6.88 MB <= proven-safe 8.19 MB):
//   invc      @ 0        (32768)   [norm_c .. gather]
//   cand      @ 32768    (458752)  [knn .. gather]
//   Fsw       @ 589824   (6291456) [norm_f .. knn]   -- dead after knn:
//     Csw       @ 589824  (1572864) [norm_c .. lse]   (overlays dead Fsw)
//     slse_part @ 2162688 (65536)   [lse .. finalize]
//     dpart     @ 2228224 (2048)
//     gpart     @ 2230272 (32768)
// ---------------------------------------------------------------------------
extern "C" void kernel_launch(void* const* d_in, const int* in_sizes, int n_in,
                              void* d_out, int out_size, void* d_ws, size_t ws_size,
                              hipStream_t stream) {
  (void)in_sizes; (void)n_in; (void)out_size; (void)ws_size;
  const float* codes = (const float*)d_in[0];   // (B,N,90)
  const float* feats = (const float*)d_in[1];   // (B,N,384)
  const float* depth = (const float*)d_in[2];   // (B,N)
  float* out = (float*)d_out;

  char* ws = (char*)d_ws;
  float*    invc      = (float*)ws;
  unsigned* cand      = (unsigned*)(ws + 32768);
  unsigned short* Fsw = (unsigned short*)(ws + 589824);
  unsigned short* Csw = (unsigned short*)(ws + 589824);
  float*    slse_part = (float*)(ws + 2162688);
  float*    dpart     = (float*)(ws + 2228224);
  float*    gpart     = (float*)(ws + 2230272);

  norm_f<<<2 * NPTS, 64, 0, stream>>>(feats, Fsw);
  knn_mfma<<<512, 512, 0, stream>>>(Fsw, cand);
  norm_c<<<2 * NPTS, 64, 0, stream>>>(codes, Csw, invc);   // Csw overlays dead Fsw
  lse_depth<<<512, 512, 0, stream>>>(Csw, depth, slse_part, dpart);
  gather_pos<<<2 * NPTS, 64, 0, stream>>>(codes, invc, cand, gpart);
  finalize<<<1, 256, 0, stream>>>(slse_part, gpart, dpart, out);
}